// Round 3
// baseline (2220.584 us; speedup 1.0000x reference)
//
#include <hip/hip_runtime.h>
#include <hip/hip_bf16.h>
#include <math.h>

#define NPTS 2048
#define NB 16
#define KNN 20
#define GP 40   // LDS pitch in bf16 elements (+8 pad: 2-way bank aliasing only)

typedef __attribute__((ext_vector_type(8))) short bf16x8;
typedef __attribute__((ext_vector_type(4))) float f32x4;

__device__ __forceinline__ float lrelu(float v) { return fmaxf(v, 0.2f * v); }

// split two floats into packed bf16 hi pair + packed bf16 lo (residual) pair
__device__ __forceinline__ void split2(float a, float b, unsigned& hp, unsigned& lp) {
    float2 f2; f2.x = a; f2.y = b;
    __hip_bfloat162 h2 = __float22bfloat162_rn(f2);
    unsigned hb; __builtin_memcpy(&hb, &h2, 4);
    float la = a - __uint_as_float(hb << 16);
    float lb = b - __uint_as_float(hb & 0xFFFF0000u);
    float2 l2; l2.x = la; l2.y = lb;
    __hip_bfloat162 k2 = __float22bfloat162_rn(l2);
    unsigned lb2; __builtin_memcpy(&lb2, &k2, 4);
    hp = hb; lp = lb2;
}

// ---- transpose x [B,N,3] -> h0 [B,3,N]
__global__ void transpose_kernel(const float* __restrict__ x, float* __restrict__ h0) {
    int t = blockIdx.x * blockDim.x + threadIdx.x;
    if (t >= NB * NPTS) return;
    int b = t / NPTS, n = t % NPTS;
    const float* src = x + (size_t)t * 3;
    float* dst = h0 + (size_t)b * 3 * NPTS + n;
    dst[0]        = src[0];
    dst[NPTS]     = src[1];
    dst[2 * NPTS] = src[2];
}

// ---- sq[b,n] = sum_c in[b,c,n]^2
__global__ void sq_kernel(const float* __restrict__ in, long bstride, int C,
                          float* __restrict__ sq) {
    int t = blockIdx.x * blockDim.x + threadIdx.x;
    if (t >= NB * NPTS) return;
    int b = t / NPTS, n = t % NPTS;
    const float* p = in + (size_t)b * bstride + n;
    float s = 0.f;
    for (int c = 0; c < C; ++c) {
        float v = p[(size_t)c * NPTS];
        s = fmaf(v, v, s);
    }
    sq[t] = s;
}

// ---- dist via MFMA: score[n][m] = 2*(X^T X)[n][m] - sq[m], bf16 hi/lo 3-pass
// grid: (16 n-tiles, 16 m-tiles, 2 batches); block 256 = 4 waves in 2x2
template<int C>
__global__ __launch_bounds__(256) void dist_mfma(const float* __restrict__ xin, long bstride,
                                                 int b0, const float* __restrict__ sq,
                                                 float* __restrict__ distbuf) {
    __shared__ __align__(16) unsigned short Ah[128 * GP];
    __shared__ __align__(16) unsigned short Al[128 * GP];
    __shared__ __align__(16) unsigned short Bh[128 * GP];
    __shared__ __align__(16) unsigned short Bl[128 * GP];

    int tn = blockIdx.x, tm = blockIdx.y, bb = blockIdx.z;
    int b = b0 + bb;
    const float* xb = xin + (size_t)b * bstride;
    float* dist = distbuf + (size_t)bb * NPTS * NPTS;

    int tid = threadIdx.x;
    int lane = tid & 63, w = tid >> 6;
    int wm = w & 1, wn = w >> 1;
    int l15 = lane & 15, q = lane >> 4;
    int col = tid & 127, kh = tid >> 7;   // staging role
    int n0 = tn * 128, m0 = tm * 128;

    f32x4 acc[4][4];
#pragma unroll
    for (int mi = 0; mi < 4; ++mi)
#pragma unroll
        for (int ni = 0; ni < 4; ++ni) acc[mi][ni] = (f32x4)0.f;

    constexpr int KS = (C + 31) / 32;
#pragma unroll 1
    for (int ks = 0; ks < KS; ++ks) {
        int c0 = ks * 32;
        {
            const float* srcA = xb + (size_t)(c0 + kh * 16) * NPTS + n0 + col;
            const float* srcB = xb + (size_t)(c0 + kh * 16) * NPTS + m0 + col;
            float va[16], vb[16];
#pragma unroll
            for (int j = 0; j < 16; ++j) {
                int kg = c0 + kh * 16 + j;
                bool ok = (kg < C);
                va[j] = ok ? srcA[(size_t)j * NPTS] : 0.f;
                vb[j] = ok ? srcB[(size_t)j * NPTS] : 0.f;
            }
            unsigned ha[8], la[8], hb[8], lb[8];
#pragma unroll
            for (int p = 0; p < 8; ++p) {
                split2(va[2 * p], va[2 * p + 1], ha[p], la[p]);
                split2(vb[2 * p], vb[2 * p + 1], hb[p], lb[p]);
            }
            unsigned short* pa = &Ah[col * GP + kh * 16];
            unsigned short* qa = &Al[col * GP + kh * 16];
            unsigned short* pb = &Bh[col * GP + kh * 16];
            unsigned short* qb = &Bl[col * GP + kh * 16];
            *(uint4*)(pa)     = make_uint4(ha[0], ha[1], ha[2], ha[3]);
            *(uint4*)(pa + 8) = make_uint4(ha[4], ha[5], ha[6], ha[7]);
            *(uint4*)(qa)     = make_uint4(la[0], la[1], la[2], la[3]);
            *(uint4*)(qa + 8) = make_uint4(la[4], la[5], la[6], la[7]);
            *(uint4*)(pb)     = make_uint4(hb[0], hb[1], hb[2], hb[3]);
            *(uint4*)(pb + 8) = make_uint4(hb[4], hb[5], hb[6], hb[7]);
            *(uint4*)(qb)     = make_uint4(lb[0], lb[1], lb[2], lb[3]);
            *(uint4*)(qb + 8) = make_uint4(lb[4], lb[5], lb[6], lb[7]);
        }
        __syncthreads();

        bf16x8 bhf[4], blf[4];
#pragma unroll
        for (int ni = 0; ni < 4; ++ni) {
            int row = wn * 64 + ni * 16 + l15;
            bhf[ni] = *(const bf16x8*)&Bh[row * GP + q * 8];
            blf[ni] = *(const bf16x8*)&Bl[row * GP + q * 8];
        }
#pragma unroll
        for (int mi = 0; mi < 4; ++mi) {
            int row = wm * 64 + mi * 16 + l15;
            bf16x8 ah = *(const bf16x8*)&Ah[row * GP + q * 8];
            bf16x8 al = *(const bf16x8*)&Al[row * GP + q * 8];
#pragma unroll
            for (int ni = 0; ni < 4; ++ni) {
                acc[mi][ni] = __builtin_amdgcn_mfma_f32_16x16x32_bf16(ah, bhf[ni], acc[mi][ni], 0, 0, 0);
                acc[mi][ni] = __builtin_amdgcn_mfma_f32_16x16x32_bf16(ah, blf[ni], acc[mi][ni], 0, 0, 0);
                acc[mi][ni] = __builtin_amdgcn_mfma_f32_16x16x32_bf16(al, bhf[ni], acc[mi][ni], 0, 0, 0);
            }
        }
        __syncthreads();
    }

#pragma unroll
    for (int ni = 0; ni < 4; ++ni) {
        int m = m0 + wn * 64 + ni * 16 + l15;
        float sv = sq[b * NPTS + m];
#pragma unroll
        for (int mi = 0; mi < 4; ++mi) {
            int nrow = n0 + wm * 64 + mi * 16 + q * 4;
#pragma unroll
            for (int r = 0; r < 4; ++r)
                dist[(size_t)(nrow + r) * NPTS + m] = 2.f * acc[mi][ni][r] - sv;
        }
    }
}

// ---- top-k selection from materialized dist rows
// block = 4 rows (wave w owns row n0+w); v[32]/lane via float4 loads
// m(lane,u) = (u>>2)*256 + lane*4 + (u&3)
__global__ __launch_bounds__(256) void knn_select(const float* __restrict__ distbuf,
                                                  int b0, int* __restrict__ idx) {
    int bb = blockIdx.y, b = b0 + bb;
    int n0 = blockIdx.x * 4;
    int tid = threadIdx.x;
    int w = tid >> 6, lane = tid & 63;
    const float* drow = distbuf + (size_t)bb * NPTS * NPTS + (size_t)(n0 + w) * NPTS;

    float v[32];
#pragma unroll
    for (int uu = 0; uu < 8; ++uu) {
        float4 f = *(const float4*)(drow + uu * 256 + lane * 4);
        v[4 * uu + 0] = f.x; v[4 * uu + 1] = f.y;
        v[4 * uu + 2] = f.z; v[4 * uu + 3] = f.w;
    }

    int* out = idx + ((size_t)b * NPTS + n0 + w) * KNN;

    float lv = v[0]; int lm = 0;
#pragma unroll
    for (int u = 1; u < 32; ++u) { if (v[u] > lv) { lv = v[u]; lm = u; } }

    for (int j = 0; j < KNN; ++j) {
        float bv = lv;
        int bm = (lm >> 2) * 256 + lane * 4 + (lm & 3);   // global m index
#pragma unroll
        for (int off = 32; off > 0; off >>= 1) {
            float ov = __shfl_down(bv, off, 64);
            int   om = __shfl_down(bm, off, 64);
            if (ov > bv || (ov == bv && om < bm)) { bv = ov; bm = om; }
        }
        bm = __shfl(bm, 0, 64);
        if (lane == 0) out[j] = bm;
        if (((bm >> 2) & 63) == lane) {   // winner lane: mark + rescan
            int u = ((bm >> 8) << 2) | (bm & 3);
#pragma unroll
            for (int qq = 0; qq < 32; ++qq) if (qq == u) v[qq] = -INFINITY;
            lv = v[0]; lm = 0;
#pragma unroll
            for (int qq = 1; qq < 32; ++qq) { if (v[qq] > lv) { lv = v[qq]; lm = qq; } }
        }
    }
}

// ---- Wa[c][o] = W[o][c]; Wd[c][o] = W[o][C+c] - W[o][c]
__global__ void prep_w_kernel(const float* __restrict__ W, int C, int O,
                              float* __restrict__ Wa, float* __restrict__ Wd) {
    int t = blockIdx.x * blockDim.x + threadIdx.x;
    if (t >= C * O) return;
    int c = t / O, o = t % O;
    float a = W[o * 2 * C + c];
    float d = W[o * 2 * C + C + c] - a;
    Wa[c * O + o] = a;
    Wd[c * O + o] = d;
}

// ---- y[b,o,m] = Wa@x_m ; base[b,off+o,n] = Wd@x_n + bias
__global__ __launch_bounds__(256) void edge_mm_kernel(const float* __restrict__ xin, long bstride,
                                                      int C, int O,
                                                      const float* __restrict__ Wa,
                                                      const float* __restrict__ Wd,
                                                      const float* __restrict__ bias,
                                                      float* __restrict__ y,
                                                      float* __restrict__ base, long base_bstride) {
    int m = blockIdx.x * 256 + threadIdx.x;
    int ngrp = O >> 3;
    int og = blockIdx.y % ngrp, b = blockIdx.y / ngrp;
    int o0 = og * 8;
    const float* xb = xin + (size_t)b * bstride + m;
    float a1[8], a2[8];
#pragma unroll
    for (int i = 0; i < 8; ++i) { a1[i] = 0.f; a2[i] = 0.f; }
#pragma unroll 2
    for (int c = 0; c < C; ++c) {
        float h = xb[(size_t)c * NPTS];
        const float* wa = Wa + c * O + o0;
        const float* wd = Wd + c * O + o0;
#pragma unroll
        for (int i = 0; i < 8; ++i) {
            a1[i] = fmaf(wa[i], h, a1[i]);
            a2[i] = fmaf(wd[i], h, a2[i]);
        }
    }
#pragma unroll
    for (int i = 0; i < 8; ++i) {
        y[((size_t)b * O + o0 + i) * NPTS + m] = a1[i];
        base[(size_t)b * base_bstride + (size_t)(o0 + i) * NPTS + m] = a2[i] + bias[o0 + i];
    }
}

// ---- feat[b,off+o,n] = lrelu( max_j y[b,o,idx[b,n,j]] + base )
__global__ __launch_bounds__(256) void gather_max_kernel(const float* __restrict__ y, int O,
                                                         const int* __restrict__ idx,
                                                         float* __restrict__ feat_slice,
                                                         long bstride) {
    __shared__ float yrow[NPTS];
    int o = blockIdx.x, b = blockIdx.y;
    const float* ysrc = y + ((size_t)b * O + o) * NPTS;
    for (int m = threadIdx.x; m < NPTS; m += 256) yrow[m] = ysrc[m];
    __syncthreads();
    float* fs = feat_slice + (size_t)b * bstride + (size_t)o * NPTS;
    const int* ib = idx + (size_t)b * NPTS * KNN;
    for (int s = 0; s < 8; ++s) {
        int n = threadIdx.x + 256 * s;
        const int* ip = ib + n * KNN;
        float mx = -INFINITY;
#pragma unroll
        for (int j = 0; j < KNN; ++j) mx = fmaxf(mx, yrow[ip[j]]);
        fs[n] = lrelu(mx + fs[n]);
    }
}

// ---- split Wf (fp32 [1024][512]) into packed bf16 hi/lo
__global__ void wf_split_kernel(const float* __restrict__ Wf,
                                unsigned* __restrict__ Wfh, unsigned* __restrict__ Wfl) {
    int t = blockIdx.x * 256 + threadIdx.x;
    if (t >= 262144) return;
    unsigned h, l;
    split2(Wf[2 * t], Wf[2 * t + 1], h, l);
    Wfh[t] = h; Wfl[t] = l;
}

// ---- final GEMM via bf16 hi/lo split MFMA, with max-over-n epilogue
__global__ __launch_bounds__(256) void final_gemm_mfma(
    const float* __restrict__ feat,
    const unsigned short* __restrict__ Wfh,
    const unsigned short* __restrict__ Wfl,
    float* __restrict__ pmax) {
    __shared__ __align__(16) unsigned short Ah[128 * GP];
    __shared__ __align__(16) unsigned short Al[128 * GP];
    __shared__ __align__(16) unsigned short Bh[128 * GP];
    __shared__ __align__(16) unsigned short Bl[128 * GP];

    int ot = blockIdx.x, nt = blockIdx.y, b = blockIdx.z;
    int o0 = ot * 128, n0 = nt * 128;
    int tid = threadIdx.x;
    int lane = tid & 63, w = tid >> 6;
    int wm = w & 1, wn = w >> 1;
    int l15 = lane & 15, q = lane >> 4;

    f32x4 acc[4][4];
#pragma unroll
    for (int mi = 0; mi < 4; ++mi)
#pragma unroll
        for (int ni = 0; ni < 4; ++ni) acc[mi][ni] = (f32x4)0.f;

    const float* fb = feat + (size_t)b * 512 * NPTS;
    int bn = tid & 127, kh = tid >> 7;

    for (int c0 = 0; c0 < 512; c0 += 32) {
#pragma unroll
        for (int p = 0; p < 2; ++p) {
            int e = p * 256 + tid;
            int r = e >> 2, qq = e & 3;
            size_t go = (size_t)(o0 + r) * 512 + c0 + qq * 8;
            *(uint4*)&Ah[r * GP + qq * 8] = *(const uint4*)(Wfh + go);
            *(uint4*)&Al[r * GP + qq * 8] = *(const uint4*)(Wfl + go);
        }
        {
            const float* src = fb + (size_t)(c0 + kh * 16) * NPTS + n0 + bn;
            float v[16];
#pragma unroll
            for (int j = 0; j < 16; ++j) v[j] = src[(size_t)j * NPTS];
            unsigned hw[8], lw[8];
#pragma unroll
            for (int p = 0; p < 8; ++p) split2(v[2 * p], v[2 * p + 1], hw[p], lw[p]);
            unsigned short* bh = &Bh[bn * GP + kh * 16];
            unsigned short* bl = &Bl[bn * GP + kh * 16];
            *(uint4*)(bh)     = make_uint4(hw[0], hw[1], hw[2], hw[3]);
            *(uint4*)(bh + 8) = make_uint4(hw[4], hw[5], hw[6], hw[7]);
            *(uint4*)(bl)     = make_uint4(lw[0], lw[1], lw[2], lw[3]);
            *(uint4*)(bl + 8) = make_uint4(lw[4], lw[5], lw[6], lw[7]);
        }
        __syncthreads();

        bf16x8 bhf[4], blf[4];
#pragma unroll
        for (int ni = 0; ni < 4; ++ni) {
            int row = wn * 64 + ni * 16 + l15;
            bhf[ni] = *(const bf16x8*)&Bh[row * GP + q * 8];
            blf[ni] = *(const bf16x8*)&Bl[row * GP + q * 8];
        }
#pragma unroll
        for (int mi = 0; mi < 4; ++mi) {
            int row = wm * 64 + mi * 16 + l15;
            bf16x8 ah = *(const bf16x8*)&Ah[row * GP + q * 8];
            bf16x8 al = *(const bf16x8*)&Al[row * GP + q * 8];
#pragma unroll
            for (int ni = 0; ni < 4; ++ni) {
                acc[mi][ni] = __builtin_amdgcn_mfma_f32_16x16x32_bf16(ah, bhf[ni], acc[mi][ni], 0, 0, 0);
                acc[mi][ni] = __builtin_amdgcn_mfma_f32_16x16x32_bf16(ah, blf[ni], acc[mi][ni], 0, 0, 0);
                acc[mi][ni] = __builtin_amdgcn_mfma_f32_16x16x32_bf16(al, bhf[ni], acc[mi][ni], 0, 0, 0);
            }
        }
        __syncthreads();
    }

    int slot = nt * 2 + wn;
#pragma unroll
    for (int mi = 0; mi < 4; ++mi) {
        float m4[4];
#pragma unroll
        for (int r = 0; r < 4; ++r) {
            float m = acc[mi][0][r];
            m = fmaxf(m, acc[mi][1][r]);
            m = fmaxf(m, acc[mi][2][r]);
            m = fmaxf(m, acc[mi][3][r]);
            m4[r] = m;
        }
#pragma unroll
        for (int off = 1; off < 16; off <<= 1) {
#pragma unroll
            for (int r = 0; r < 4; ++r)
                m4[r] = fmaxf(m4[r], __shfl_xor(m4[r], off, 16));
        }
        if (l15 == 0) {
            int mbase = o0 + wm * 64 + mi * 16 + q * 4;
#pragma unroll
            for (int r = 0; r < 4; ++r)
                pmax[((size_t)b * 1024 + mbase + r) * 32 + slot] = m4[r];
        }
    }
}

__global__ void final_reduce_kernel(const float* __restrict__ pmax,
                                    const float* __restrict__ bf,
                                    float* __restrict__ out) {
    int t = blockIdx.x * blockDim.x + threadIdx.x;
    if (t >= NB * 1024) return;
    const float* p = pmax + (size_t)t * 32;
    float m = p[0];
#pragma unroll
    for (int i = 1; i < 32; ++i) m = fmaxf(m, p[i]);
    out[t] = lrelu(m + bf[t & 1023]);
}

extern "C" void kernel_launch(void* const* d_in, const int* in_sizes, int n_in,
                              void* d_out, int out_size, void* d_ws, size_t ws_size,
                              hipStream_t stream) {
    const float* x  = (const float*)d_in[0];
    const float* W[4]  = {(const float*)d_in[1], (const float*)d_in[3],
                          (const float*)d_in[5], (const float*)d_in[7]};
    const float* bb[4] = {(const float*)d_in[2], (const float*)d_in[4],
                          (const float*)d_in[6], (const float*)d_in[8]};
    const float* Wf = (const float*)d_in[9];
    const float* bf = (const float*)d_in[10];
    float* out = (float*)d_out;

    float* ws   = (float*)d_ws;
    float* h0   = ws;                       // B*3*N      = 98304
    float* sq   = h0 + 98304;               // B*N        = 32768
    int*   idx  = (int*)(sq + 32768);       // B*N*20     = 655360
    float* y    = (float*)(idx + 655360);   // B*256*N    = 8388608 (also dist chunk + final bufs)
    float* feat = y + 8388608;              // B*512*N    = 16777216
    float* Wa   = feat + 16777216 + 262144; // 128*256    = 32768
    float* Wd   = Wa + 32768;               // 128*256    = 32768

    // carved out of the y region (dead at the relevant times):
    unsigned* Wfh = (unsigned*)y;                    // 262144 dwords
    unsigned* Wfl = (unsigned*)(y + 262144);         // 262144 dwords
    float*    pmax = y + 524288;                     // 16*1024*32 = 524288 floats

    transpose_kernel<<<128, 256, 0, stream>>>(x, h0);

    const int  Cs[4]   = {3, 64, 64, 128};
    const int  Os[4]   = {64, 64, 128, 256};
    const int  offs[4] = {0, 64, 128, 256};

    for (int l = 0; l < 4; ++l) {
        const float* in = (l == 0) ? h0 : feat + (size_t)offs[l - 1] * NPTS;
        long bstr = (l == 0) ? (long)3 * NPTS : (long)512 * NPTS;
        int C = Cs[l], O = Os[l];

        sq_kernel<<<128, 256, 0, stream>>>(in, bstr, C, sq);

        // kNN: dist chunk (2 batches, 32 MB in y) -> register top-k
        for (int b0 = 0; b0 < NB; b0 += 2) {
            dim3 dg(16, 16, 2);
            if (C == 3)       dist_mfma<3>  <<<dg, 256, 0, stream>>>(in, bstr, b0, sq, y);
            else if (C == 64) dist_mfma<64> <<<dg, 256, 0, stream>>>(in, bstr, b0, sq, y);
            else              dist_mfma<128><<<dg, 256, 0, stream>>>(in, bstr, b0, sq, y);
            knn_select<<<dim3(512, 2), 256, 0, stream>>>(y, b0, idx);
        }

        prep_w_kernel<<<(C * O + 255) / 256, 256, 0, stream>>>(W[l], C, O, Wa, Wd);

        float* fslice = feat + (size_t)offs[l] * NPTS;
        edge_mm_kernel<<<dim3(NPTS / 256, NB * (O >> 3)), 256, 0, stream>>>(
            in, bstr, C, O, Wa, Wd, bb[l], y, fslice, (long)512 * NPTS);

        gather_max_kernel<<<dim3(O, NB), 256, 0, stream>>>(y, O, idx, fslice, (long)512 * NPTS);
    }

    wf_split_kernel<<<1024, 256, 0, stream>>>(Wf, Wfh, Wfl);
    final_gemm_mfma<<<dim3(8, 16, NB), 256, 0, stream>>>(
        feat, (const unsigned short*)Wfh, (const unsigned short*)Wfl, pmax);
    final_reduce_kernel<<<64, 256, 0, stream>>>(pmax, bf, out);
}